// Round 1
// baseline (2346.336 us; speedup 1.0000x reference)
//
#include <hip/hip_runtime.h>
#include <cmath>

#define BS    64          // samples per block
#define NT    512         // threads per block (8 waves)
#define HDIM  64
#define T1    50
#define T2    100
#define BATCH 8192
#define NBLK  (BATCH/BS)  // 128

// ---- workspace layout (float offsets) ----
#define OFF_FC1T   ((size_t)0)
#define SZ_FC1T    ((size_t)T1*BATCH)                 // 409600
#define OFF_HS1T   (OFF_FC1T + SZ_FC1T)
#define SZ_HS1T    ((size_t)NBLK*T1*128*BS)           // 52428800
#define OFF_WHHT1  (OFF_HS1T + SZ_HS1T)
#define SZ_WHHT    ((size_t)2*64*256)                 // 32768
#define OFF_WHHT2  (OFF_WHHT1 + SZ_WHHT)
#define OFF_WIHT2  (OFF_WHHT2 + SZ_WHHT)
#define SZ_WIHT2   ((size_t)2*128*256)                // 65536
#define OFF_PART   (OFF_WIHT2 + SZ_WIHT2)
#define SZ_PART    ((size_t)2*T2*BATCH)               // 1638400

__device__ __forceinline__ float rcp_(float x) { return __builtin_amdgcn_rcpf(x); }
__device__ __forceinline__ float sig_(float x) {
    return rcp_(1.f + exp2f(-1.4426950408889634f * x));
}
__device__ __forceinline__ float tanh_(float x) {
    return 1.f - 2.f * rcp_(1.f + exp2f(2.885390081777927f * x));
}

// ---------------- weight transpose prep ----------------
__global__ void k_prep(const float* __restrict__ whh1f, const float* __restrict__ whh1b,
                       const float* __restrict__ whh2f, const float* __restrict__ whh2b,
                       const float* __restrict__ wih2f, const float* __restrict__ wih2b,
                       float* __restrict__ ws) {
    float* WhhT1 = ws + OFF_WHHT1;  // [2][64][256]
    float* WhhT2 = ws + OFF_WHHT2;  // [2][64][256]
    float* WihT2 = ws + OFF_WIHT2;  // [2][128][256]
    const int n = 32768 + 32768 + 65536;
    for (int i = blockIdx.x * blockDim.x + threadIdx.x; i < n;
         i += gridDim.x * blockDim.x) {
        if (i < 32768) {
            int d = i >> 14, r = i & 16383, k = r >> 8, j = r & 255;
            const float* src = d ? whh1b : whh1f;       // [256][64]
            WhhT1[i] = src[j * 64 + k];
        } else if (i < 65536) {
            int i2 = i - 32768;
            int d = i2 >> 14, r = i2 & 16383, k = r >> 8, j = r & 255;
            const float* src = d ? whh2b : whh2f;       // [256][64]
            WhhT2[i2] = src[j * 64 + k];
        } else {
            int i2 = i - 65536;
            int d = i2 >> 15, r = i2 & 32767, k = r >> 8, j = r & 255;
            const float* src = d ? wih2b : wih2f;       // [256][128]
            WihT2[i2] = src[j * 128 + k];
        }
    }
}

// ---------------- fc1: fc1T[t][b] = x[b]·fc1_w[t] + fc1_b[t] ----------------
__global__ __launch_bounds__(256) void k_fc1(const float* __restrict__ x,
                                             const float* __restrict__ w,
                                             const float* __restrict__ b,
                                             float* __restrict__ fc1T) {
    __shared__ float wls[1000];
    __shared__ float bls[50];
    int tid = threadIdx.x;
    for (int i = tid; i < 1000; i += 256) wls[i] = w[i];
    if (tid < 50) bls[tid] = b[tid];
    __syncthreads();
    int bidx = blockIdx.x * 256 + tid;
    float xv[20];
#pragma unroll
    for (int i = 0; i < 20; ++i) xv[i] = x[bidx * 20 + i];
    for (int t = 0; t < T1; ++t) {
        float s = bls[t];
#pragma unroll
        for (int i = 0; i < 20; ++i) s += xv[i] * wls[t * 20 + i];
        fc1T[t * BATCH + bidx] = s;
    }
}

// ---------------- layer-1 BiLSTM (input size 1) ----------------
// block = (sample-block, dir); lane = sample; wave w owns hidden jh0=w*8..+8 (all 4 gates)
__global__ __launch_bounds__(NT, 2) void k_lstm1(
    const float* __restrict__ wih1f, const float* __restrict__ b1f,
    const float* __restrict__ wih1b, const float* __restrict__ b1b,
    const float* __restrict__ whhT1, const float* __restrict__ fc1T,
    float* __restrict__ hs1T) {
    __shared__ float Ht[64][64];     // Ht[k][s]
    __shared__ float x1[T1][64];
    int tid  = threadIdx.x;
    int lane = tid & 63;
    int wu   = __builtin_amdgcn_readfirstlane(tid >> 6);
    int dir  = blockIdx.y;
    int bblk = blockIdx.x;
    int s0   = bblk * BS;

    for (int i = tid; i < T1 * 64; i += NT) {
        int t = i >> 6, s = i & 63;
        x1[t][s] = fc1T[t * BATCH + s0 + s];
    }
    for (int i = tid; i < 64 * 64; i += NT) ((float*)Ht)[i] = 0.f;

    const float* wih = dir ? wih1b : wih1f;
    const float* bia = dir ? b1b : b1f;
    int jh0 = wu * 8;
    int j4  = wu * 2;
    float wv[4][8], bv[4][8];
#pragma unroll
    for (int g = 0; g < 4; ++g)
#pragma unroll
        for (int jj = 0; jj < 8; ++jj) {
            wv[g][jj] = wih[g * 64 + jh0 + jj];
            bv[g][jj] = bia[g * 64 + jh0 + jj];
        }
    const float4* wT = (const float4*)(whhT1 + (size_t)dir * 16384);  // [k][64 float4]
    float c[8];
#pragma unroll
    for (int jj = 0; jj < 8; ++jj) c[jj] = 0.f;
    __syncthreads();

    for (int step = 0; step < T1; ++step) {
        int t = dir ? (T1 - 1 - step) : step;
        float xs = x1[t][lane];
        float acc[4][8];
#pragma unroll
        for (int g = 0; g < 4; ++g)
#pragma unroll
            for (int jj = 0; jj < 8; ++jj) acc[g][jj] = xs * wv[g][jj] + bv[g][jj];

#pragma unroll 4
        for (int k = 0; k < 64; ++k) {
            float h = Ht[k][lane];
            const float4* row = wT + k * 64;
#pragma unroll
            for (int g = 0; g < 4; ++g) {
                float4 a = row[g * 16 + j4];
                float4 b4 = row[g * 16 + j4 + 1];
                acc[g][0] += h * a.x;  acc[g][1] += h * a.y;
                acc[g][2] += h * a.z;  acc[g][3] += h * a.w;
                acc[g][4] += h * b4.x; acc[g][5] += h * b4.y;
                acc[g][6] += h * b4.z; acc[g][7] += h * b4.w;
            }
        }

        float hnew[8];
#pragma unroll
        for (int jj = 0; jj < 8; ++jj) {
            float ig = sig_(acc[0][jj]);
            float fg = sig_(acc[1][jj]);
            float gg = tanh_(acc[2][jj]);
            float og = sig_(acc[3][jj]);
            c[jj] = fg * c[jj] + ig * gg;
            hnew[jj] = og * tanh_(c[jj]);
        }
        __syncthreads();
        size_t gbase = (((size_t)(bblk * T1 + t)) * 128 + dir * 64 + jh0) * 64 + lane;
#pragma unroll
        for (int jj = 0; jj < 8; ++jj) {
            Ht[jh0 + jj][lane] = hnew[jj];
            hs1T[gbase + (size_t)jj * 64] = hnew[jj];
        }
        __syncthreads();
    }
}

// ---------------- layer-2 BiLSTM (input 128 = repeated hs1) + fused fc2 partial ----------------
__global__ __launch_bounds__(NT, 2) void k_lstm2(
    const float* __restrict__ b2f, const float* __restrict__ b2b,
    const float* __restrict__ fc2w,
    const float* __restrict__ whhT2, const float* __restrict__ wihT2,
    const float* __restrict__ hs1T, float* __restrict__ part) {
    __shared__ float Ht[64][64];    // Ht[k][s]
    __shared__ float Xt[128][64];   // Xt[c][s]
    __shared__ float fc2s[64];
    int tid  = threadIdx.x;
    int lane = tid & 63;
    int wu   = __builtin_amdgcn_readfirstlane(tid >> 6);
    int dir  = blockIdx.y;
    int bblk = blockIdx.x;
    int s0   = bblk * BS;

    if (tid < 64) fc2s[tid] = fc2w[dir * 64 + tid];
    for (int i = tid; i < 64 * 64; i += NT) ((float*)Ht)[i] = 0.f;

    const float* bia = dir ? b2b : b2f;
    int jh0 = wu * 8;
    int j4  = wu * 2;
    const float4* wT  = (const float4*)(whhT2 + (size_t)dir * 16384);
    const float4* wiT = (const float4*)(wihT2 + (size_t)dir * 32768);
    float bv[4][8];
#pragma unroll
    for (int g = 0; g < 4; ++g)
#pragma unroll
        for (int jj = 0; jj < 8; ++jj) bv[g][jj] = bia[g * 64 + jh0 + jj];

    float c[8], xgs[4][8];
#pragma unroll
    for (int jj = 0; jj < 8; ++jj) c[jj] = 0.f;
    __syncthreads();

    for (int step = 0; step < T2; ++step) {
        int t2 = dir ? (T2 - 1 - step) : step;
        if ((step & 1) == 0) {           // new time-pair: stage X, recompute input proj
            int tp = t2 >> 1;
            __syncthreads();
            const float4* src = (const float4*)(hs1T + ((size_t)(bblk * T1 + tp)) * 128 * 64);
            float4* dst = (float4*)&Xt[0][0];
            for (int i = tid; i < 2048; i += NT) dst[i] = src[i];
            __syncthreads();
#pragma unroll
            for (int g = 0; g < 4; ++g)
#pragma unroll
                for (int jj = 0; jj < 8; ++jj) xgs[g][jj] = bv[g][jj];
#pragma unroll 4
            for (int k = 0; k < 128; ++k) {
                float xv = Xt[k][lane];
                const float4* row = wiT + k * 64;
#pragma unroll
                for (int g = 0; g < 4; ++g) {
                    float4 a = row[g * 16 + j4];
                    float4 b4 = row[g * 16 + j4 + 1];
                    xgs[g][0] += xv * a.x;  xgs[g][1] += xv * a.y;
                    xgs[g][2] += xv * a.z;  xgs[g][3] += xv * a.w;
                    xgs[g][4] += xv * b4.x; xgs[g][5] += xv * b4.y;
                    xgs[g][6] += xv * b4.z; xgs[g][7] += xv * b4.w;
                }
            }
        }

        float acc[4][8];
#pragma unroll
        for (int g = 0; g < 4; ++g)
#pragma unroll
            for (int jj = 0; jj < 8; ++jj) acc[g][jj] = xgs[g][jj];

#pragma unroll 4
        for (int k = 0; k < 64; ++k) {
            float h = Ht[k][lane];
            const float4* row = wT + k * 64;
#pragma unroll
            for (int g = 0; g < 4; ++g) {
                float4 a = row[g * 16 + j4];
                float4 b4 = row[g * 16 + j4 + 1];
                acc[g][0] += h * a.x;  acc[g][1] += h * a.y;
                acc[g][2] += h * a.z;  acc[g][3] += h * a.w;
                acc[g][4] += h * b4.x; acc[g][5] += h * b4.y;
                acc[g][6] += h * b4.z; acc[g][7] += h * b4.w;
            }
        }

        float hnew[8];
#pragma unroll
        for (int jj = 0; jj < 8; ++jj) {
            float ig = sig_(acc[0][jj]);
            float fg = sig_(acc[1][jj]);
            float gg = tanh_(acc[2][jj]);
            float og = sig_(acc[3][jj]);
            c[jj] = fg * c[jj] + ig * gg;
            hnew[jj] = og * tanh_(c[jj]);
        }
        __syncthreads();
#pragma unroll
        for (int jj = 0; jj < 8; ++jj) Ht[jh0 + jj][lane] = hnew[jj];
        __syncthreads();

        if (wu == 0) {  // fused fc2 partial for this direction
            float p = 0.f;
#pragma unroll 8
            for (int jh = 0; jh < 64; ++jh) p += fc2s[jh] * Ht[jh][lane];
            part[((size_t)dir * T2 + t2) * BATCH + s0 + lane] = p;
        }
    }
}

// ---------------- combine fc2 partials + tanh ----------------
__global__ __launch_bounds__(256) void k_fc2(const float* __restrict__ part,
                                             const float* __restrict__ fc2b,
                                             float* __restrict__ out) {
    int u = blockIdx.x * 256 + threadIdx.x;
    if (u >= BATCH * T2) return;
    int b = u / T2, t = u - b * T2;
    float p = part[(size_t)t * BATCH + b] + part[((size_t)T2 + t) * BATCH + b] + fc2b[0];
    out[u] = tanh_(p);
}

extern "C" void kernel_launch(void* const* d_in, const int* in_sizes, int n_in,
                              void* d_out, int out_size, void* d_ws, size_t ws_size,
                              hipStream_t stream) {
    const float* x      = (const float*)d_in[0];
    const float* fc1w   = (const float*)d_in[1];
    const float* fc1b   = (const float*)d_in[2];
    const float* r1wihf = (const float*)d_in[3];
    const float* r1whhf = (const float*)d_in[4];
    const float* r1bf   = (const float*)d_in[5];
    const float* r1wihb = (const float*)d_in[6];
    const float* r1whhb = (const float*)d_in[7];
    const float* r1bb   = (const float*)d_in[8];
    const float* r2wihf = (const float*)d_in[9];
    const float* r2whhf = (const float*)d_in[10];
    const float* r2bf   = (const float*)d_in[11];
    const float* r2wihb = (const float*)d_in[12];
    const float* r2whhb = (const float*)d_in[13];
    const float* r2bb   = (const float*)d_in[14];
    const float* fc2w   = (const float*)d_in[15];
    const float* fc2b   = (const float*)d_in[16];
    float* ws  = (float*)d_ws;
    float* out = (float*)d_out;

    k_prep<<<64, 256, 0, stream>>>(r1whhf, r1whhb, r2whhf, r2whhb, r2wihf, r2wihb, ws);
    k_fc1<<<BATCH / 256, 256, 0, stream>>>(x, fc1w, fc1b, ws + OFF_FC1T);
    dim3 g1(NBLK, 2);
    k_lstm1<<<g1, NT, 0, stream>>>(r1wihf, r1bf, r1wihb, r1bb,
                                   ws + OFF_WHHT1, ws + OFF_FC1T, ws + OFF_HS1T);
    k_lstm2<<<g1, NT, 0, stream>>>(r2bf, r2bb, fc2w,
                                   ws + OFF_WHHT2, ws + OFF_WIHT2,
                                   ws + OFF_HS1T, ws + OFF_PART);
    k_fc2<<<(BATCH * T2 + 255) / 256, 256, 0, stream>>>(ws + OFF_PART, fc2b, out);
}

// Round 2
// 578.173 us; speedup vs baseline: 4.0582x; 4.0582x over previous
//
#include <hip/hip_runtime.h>
#include <cmath>

#define H1    64
#define T1    50
#define T2    100
#define BATCH 8192
#define NBLK  128

typedef __attribute__((ext_vector_type(8))) short s16x8;
typedef __attribute__((ext_vector_type(4))) float f32x4;

#define MFMA16(a,b,c) __builtin_amdgcn_mfma_f32_16x16x32_bf16(a,b,c,0,0,0)

// ---- workspace byte offsets ----
#define OFF_FC1T  ((size_t)0)                                   // fp32 T1*BATCH
#define OFF_XF    ((size_t)1638400)                             // ushort NBLK*T1*4*4*64*8
#define OFF_WA1   ((size_t)(1638400 + 104857600))               // ushort 32768
#define OFF_WA2HH (OFF_WA1 + 65536)                             // ushort 32768
#define OFF_WA2IH (OFF_WA2HH + 65536)                           // ushort 65536
#define OFF_PART  (OFF_WA2IH + 131072)                          // fp32 2*T2*BATCH

__device__ __forceinline__ float rcp_(float x) { return __builtin_amdgcn_rcpf(x); }
__device__ __forceinline__ float sig_(float x) {
    return rcp_(1.f + exp2f(-1.4426950408889634f * x));
}
__device__ __forceinline__ float tanh_(float x) {
    return 1.f - 2.f * rcp_(1.f + exp2f(2.885390081777927f * x));
}
__device__ __forceinline__ unsigned short bf16_rne(float x) {
    unsigned int u = __float_as_uint(x);
    u += 0x7fffu + ((u >> 16) & 1u);
    return (unsigned short)(u >> 16);
}
__device__ __forceinline__ float bf16f(unsigned short h) {
    return __uint_as_float(((unsigned int)h) << 16);
}

// ---------------- prep: weights -> bf16 A-fragment layout ----------------
// A-frag (16x16x32): lane l holds A[m = l&15][k = (l>>4)*8 + j], j=0..7
// WA1 / WA2HH: [dir][mt(16)][kk(2)][l(64)][j(8)];  WA2IH: [dir][mt(16)][kk(4)][l(64)][j(8)]
__global__ __launch_bounds__(256) void k_prep(
    const float* __restrict__ whh1f, const float* __restrict__ whh1b,
    const float* __restrict__ whh2f, const float* __restrict__ whh2b,
    const float* __restrict__ wih2f, const float* __restrict__ wih2b,
    unsigned short* __restrict__ WA1, unsigned short* __restrict__ WA2HH,
    unsigned short* __restrict__ WA2IH)
{
    int i = blockIdx.x * 256 + threadIdx.x;     // 16384 slots
    if (i < 8192) {
        int a   = i >> 12;                      // 0: layer1 whh, 1: layer2 whh
        int r   = i & 4095;
        int dir = r >> 11, rem = r & 2047;
        int mt  = rem >> 7, rem2 = rem & 127;
        int kk  = rem2 >> 6, l = rem2 & 63;
        const float* s_ = a ? (dir ? whh2b : whh2f) : (dir ? whh1b : whh1f);
        unsigned short* d_ = a ? WA2HH : WA1;
        int gate = mt * 16 + (l & 15);
        int k0   = kk * 32 + (l >> 4) * 8;
        const float* p = s_ + gate * 64 + k0;
        unsigned short* q = d_ + (size_t)r * 8;
#pragma unroll
        for (int j = 0; j < 8; ++j) q[j] = bf16_rne(p[j]);
    } else {
        int r   = i - 8192;                     // layer2 wih, 8192 slots
        int dir = r >> 12, rem = r & 4095;
        int mt  = rem >> 8, rem2 = rem & 255;
        int kk  = rem2 >> 6, l = rem2 & 63;
        const float* s_ = dir ? wih2b : wih2f;
        int gate = mt * 16 + (l & 15);
        int k0   = kk * 32 + (l >> 4) * 8;
        const float* p = s_ + gate * 128 + k0;
        unsigned short* q = WA2IH + (size_t)r * 8;
#pragma unroll
        for (int j = 0; j < 8; ++j) q[j] = bf16_rne(p[j]);
    }
}

// ---------------- fc1 ----------------
__global__ __launch_bounds__(256) void k_fc1(const float* __restrict__ x,
                                             const float* __restrict__ w,
                                             const float* __restrict__ b,
                                             float* __restrict__ fc1T) {
    __shared__ float wls[1000];
    __shared__ float bls[50];
    int tid = threadIdx.x;
    for (int i = tid; i < 1000; i += 256) wls[i] = w[i];
    if (tid < 50) bls[tid] = b[tid];
    __syncthreads();
    int bidx = blockIdx.x * 256 + tid;
    float xv[20];
#pragma unroll
    for (int i = 0; i < 20; ++i) xv[i] = x[bidx * 20 + i];
    for (int t = 0; t < T1; ++t) {
        float s = bls[t];
#pragma unroll
        for (int i = 0; i < 20; ++i) s += xv[i] * wls[t * 20 + i];
        fc1T[t * BATCH + bidx] = s;
    }
}

// ---------------- layer-1 BiLSTM: MFMA recurrent, scalar input-proj ----------------
// block (bblk, dir); 8 waves = wh(4 hidden-groups of 16) x wsh(2 sample-halves of 32)
// wave owns M-tiles {g*4+wh}, N-tiles {wsh*2, wsh*2+1}
__global__ __launch_bounds__(512, 2) void k_lstm1(
    const float* __restrict__ wih1f, const float* __restrict__ b1f,
    const float* __restrict__ wih1b, const float* __restrict__ b1b,
    const unsigned short* __restrict__ WA1,
    const float* __restrict__ fc1T,
    unsigned short* __restrict__ XF)
{
    __shared__ float x1s[T1][64];
    __shared__ unsigned short Htf[2][2][2][4][64][8];   // [buf][half][kk][nt][l][j]
    int tid  = threadIdx.x;
    int lane = tid & 63;
    int w    = __builtin_amdgcn_readfirstlane(tid >> 6);
    int wh   = w & 3, wsh = w >> 2;
    int quad = lane >> 4, col = lane & 15;
    int dir  = blockIdx.y, bblk = blockIdx.x;

    for (int i = tid; i < T1 * 64; i += 512) {
        int t = i >> 6, s = i & 63;
        x1s[t][s] = fc1T[t * BATCH + bblk * 64 + s];
    }
    const float* wih = dir ? wih1b : wih1f;
    const float* bia = dir ? b1b : b1f;
    float wv[4][4], bv[4][4];
#pragma unroll
    for (int g = 0; g < 4; ++g)
#pragma unroll
        for (int r = 0; r < 4; ++r) {
            int gate = g * 64 + wh * 16 + quad * 4 + r;
            wv[g][r] = wih[gate];
            bv[g][r] = bia[gate];
        }
    s16x8 whhA[4][2];
#pragma unroll
    for (int g = 0; g < 4; ++g)
#pragma unroll
        for (int kk = 0; kk < 2; ++kk)
            whhA[g][kk] = *(const s16x8*)(WA1 +
                ((size_t)((dir * 16 + (g * 4 + wh)) * 2 + kk) * 64 + lane) * 8);

    float c[2][4];
#pragma unroll
    for (int nt = 0; nt < 2; ++nt)
#pragma unroll
        for (int r = 0; r < 4; ++r) c[nt][r] = 0.f;

    int lq  = (2 * wh + (quad >> 1)) & 3;   // consumer quad group for our k-rows
    int lp  = lq * 16 + col;
    int jo  = (quad & 1) * 4;               // ushort offset within 8-elem slot
    int kkw = wh >> 1;                      // recurrent-frag kk of our k-rows
    int kk1 = dir * 2 + (wh >> 1);          // layer-2 X-frag kk (k = dir*64 + j)
    __syncthreads();
    int buf = 0;
    for (int step = 0; step < T1; ++step) {
        int t = dir ? (T1 - 1 - step) : step;
        float xt[2];
        xt[0] = x1s[t][wsh * 32 + col];
        xt[1] = x1s[t][wsh * 32 + 16 + col];
        f32x4 acc[4][2];
#pragma unroll
        for (int g = 0; g < 4; ++g)
#pragma unroll
            for (int nt = 0; nt < 2; ++nt)
#pragma unroll
                for (int r = 0; r < 4; ++r)
                    acc[g][nt][r] = bv[g][r] + wv[g][r] * xt[nt];
        if (step) {
            s16x8 hb[2][2][2];              // [half][kk][nt]
#pragma unroll
            for (int hf = 0; hf < 2; ++hf)
#pragma unroll
                for (int kk = 0; kk < 2; ++kk)
#pragma unroll
                    for (int nt = 0; nt < 2; ++nt)
                        hb[hf][kk][nt] = *(const s16x8*)&Htf[buf][hf][kk][wsh * 2 + nt][lane][0];
#pragma unroll
            for (int g = 0; g < 4; ++g)
#pragma unroll
                for (int nt = 0; nt < 2; ++nt) {
                    f32x4 a = acc[g][nt];
                    a = MFMA16(whhA[g][0], hb[0][0][nt], a);
                    a = MFMA16(whhA[g][1], hb[0][1][nt], a);
                    a = MFMA16(whhA[g][0], hb[1][0][nt], a);
                    a = MFMA16(whhA[g][1], hb[1][1][nt], a);
                    acc[g][nt] = a;
                }
        }
        int nbuf = buf ^ 1;
#pragma unroll
        for (int nt = 0; nt < 2; ++nt) {
            unsigned short hh[4], hl[4];
#pragma unroll
            for (int r = 0; r < 4; ++r) {
                float iv = acc[0][nt][r], fv = acc[1][nt][r];
                float gv = acc[2][nt][r], ov = acc[3][nt][r];
                float cc = sig_(fv) * c[nt][r] + sig_(iv) * tanh_(gv);
                c[nt][r] = cc;
                float h = sig_(ov) * tanh_(cc);
                hh[r] = bf16_rne(h);
                hl[r] = bf16_rne(h - bf16f(hh[r]));
            }
            uint2 vhi, vlo;
            vhi.x = (unsigned)hh[0] | ((unsigned)hh[1] << 16);
            vhi.y = (unsigned)hh[2] | ((unsigned)hh[3] << 16);
            vlo.x = (unsigned)hl[0] | ((unsigned)hl[1] << 16);
            vlo.y = (unsigned)hl[2] | ((unsigned)hl[3] << 16);
            int ntg = wsh * 2 + nt;
            *(uint2*)&Htf[nbuf][0][kkw][ntg][lp][jo] = vhi;
            *(uint2*)&Htf[nbuf][1][kkw][ntg][lp][jo] = vlo;
            *(uint2*)(XF + ((((size_t)(bblk * T1 + t) * 4 + kk1) * 4 + ntg) * 64 + lp) * 8 + jo) = vhi;
        }
        __syncthreads();
        buf = nbuf;
    }
}

// ---------------- layer-2 BiLSTM: MFMA input-proj (per pair) + MFMA recurrent + fused fc2 ----------------
__global__ __launch_bounds__(512, 2) void k_lstm2(
    const float* __restrict__ b2f, const float* __restrict__ b2b,
    const float* __restrict__ fc2w,
    const unsigned short* __restrict__ WA2HH,
    const unsigned short* __restrict__ WA2IH,
    const unsigned short* __restrict__ XF,
    float* __restrict__ part)
{
    __shared__ unsigned short Htf[2][2][2][4][64][8];
    __shared__ float partb[2][64];
    int tid  = threadIdx.x;
    int lane = tid & 63;
    int w    = __builtin_amdgcn_readfirstlane(tid >> 6);
    int wh   = w & 3, wsh = w >> 2;
    int quad = lane >> 4, col = lane & 15;
    int dir  = blockIdx.y, bblk = blockIdx.x;

    if (tid < 128) partb[tid >> 6][tid & 63] = 0.f;

    const float* bia = dir ? b2b : b2f;
    float bv[4][4], f2v[4];
#pragma unroll
    for (int g = 0; g < 4; ++g)
#pragma unroll
        for (int r = 0; r < 4; ++r)
            bv[g][r] = bia[g * 64 + wh * 16 + quad * 4 + r];
#pragma unroll
    for (int r = 0; r < 4; ++r)
        f2v[r] = fc2w[dir * 64 + wh * 16 + quad * 4 + r];

    s16x8 whhA[4][2];
#pragma unroll
    for (int g = 0; g < 4; ++g)
#pragma unroll
        for (int kk = 0; kk < 2; ++kk)
            whhA[g][kk] = *(const s16x8*)(WA2HH +
                ((size_t)((dir * 16 + (g * 4 + wh)) * 2 + kk) * 64 + lane) * 8);

    float c[2][4];
#pragma unroll
    for (int nt = 0; nt < 2; ++nt)
#pragma unroll
        for (int r = 0; r < 4; ++r) c[nt][r] = 0.f;

    int lq  = (2 * wh + (quad >> 1)) & 3;
    int lp  = lq * 16 + col;
    int jo  = (quad & 1) * 4;
    int kkw = wh >> 1;
    f32x4 xacc[4][2];
    __syncthreads();
    int buf = 0;
    for (int step = 0; step < T2; ++step) {
        int t2 = dir ? (T2 - 1 - step) : step;
        if ((step & 1) == 0) {              // new time-pair: input projection via MFMA
            int tp = t2 >> 1;
            s16x8 xb[4][2], wA[4][4];
#pragma unroll
            for (int kk = 0; kk < 4; ++kk)
#pragma unroll
                for (int nt = 0; nt < 2; ++nt)
                    xb[kk][nt] = *(const s16x8*)(XF +
                        ((((size_t)(bblk * T1 + tp) * 4 + kk) * 4 + (wsh * 2 + nt)) * 64 + lane) * 8);
#pragma unroll
            for (int g = 0; g < 4; ++g)
#pragma unroll
                for (int kk = 0; kk < 4; ++kk)
                    wA[g][kk] = *(const s16x8*)(WA2IH +
                        ((size_t)((dir * 16 + (g * 4 + wh)) * 4 + kk) * 64 + lane) * 8);
#pragma unroll
            for (int g = 0; g < 4; ++g)
#pragma unroll
                for (int nt = 0; nt < 2; ++nt) {
                    f32x4 a;
                    a[0] = bv[g][0]; a[1] = bv[g][1]; a[2] = bv[g][2]; a[3] = bv[g][3];
                    a = MFMA16(wA[g][0], xb[0][nt], a);
                    a = MFMA16(wA[g][1], xb[1][nt], a);
                    a = MFMA16(wA[g][2], xb[2][nt], a);
                    a = MFMA16(wA[g][3], xb[3][nt], a);
                    xacc[g][nt] = a;
                }
        }
        f32x4 acc[4][2];
        if (step) {
            s16x8 hb[2][2][2];
#pragma unroll
            for (int hf = 0; hf < 2; ++hf)
#pragma unroll
                for (int kk = 0; kk < 2; ++kk)
#pragma unroll
                    for (int nt = 0; nt < 2; ++nt)
                        hb[hf][kk][nt] = *(const s16x8*)&Htf[buf][hf][kk][wsh * 2 + nt][lane][0];
#pragma unroll
            for (int g = 0; g < 4; ++g)
#pragma unroll
                for (int nt = 0; nt < 2; ++nt) {
                    f32x4 a = xacc[g][nt];
                    a = MFMA16(whhA[g][0], hb[0][0][nt], a);
                    a = MFMA16(whhA[g][1], hb[0][1][nt], a);
                    a = MFMA16(whhA[g][0], hb[1][0][nt], a);
                    a = MFMA16(whhA[g][1], hb[1][1][nt], a);
                    acc[g][nt] = a;
                }
        } else {
#pragma unroll
            for (int g = 0; g < 4; ++g)
#pragma unroll
                for (int nt = 0; nt < 2; ++nt) acc[g][nt] = xacc[g][nt];
        }
        int nbuf = buf ^ 1;
#pragma unroll
        for (int nt = 0; nt < 2; ++nt) {
            unsigned short hh[4], hl[4];
            float pacc = 0.f;
#pragma unroll
            for (int r = 0; r < 4; ++r) {
                float iv = acc[0][nt][r], fv = acc[1][nt][r];
                float gv = acc[2][nt][r], ov = acc[3][nt][r];
                float cc = sig_(fv) * c[nt][r] + sig_(iv) * tanh_(gv);
                c[nt][r] = cc;
                float h = sig_(ov) * tanh_(cc);
                pacc += f2v[r] * h;
                hh[r] = bf16_rne(h);
                hl[r] = bf16_rne(h - bf16f(hh[r]));
            }
            uint2 vhi, vlo;
            vhi.x = (unsigned)hh[0] | ((unsigned)hh[1] << 16);
            vhi.y = (unsigned)hh[2] | ((unsigned)hh[3] << 16);
            vlo.x = (unsigned)hl[0] | ((unsigned)hl[1] << 16);
            vlo.y = (unsigned)hl[2] | ((unsigned)hl[3] << 16);
            int ntg = wsh * 2 + nt;
            *(uint2*)&Htf[nbuf][0][kkw][ntg][lp][jo] = vhi;
            *(uint2*)&Htf[nbuf][1][kkw][ntg][lp][jo] = vlo;
            atomicAdd(&partb[step & 1][ntg * 16 + col], pacc);
        }
        __syncthreads();
        if (w == 0) {
            part[((size_t)(dir * T2 + t2)) * BATCH + bblk * 64 + lane] = partb[step & 1][lane];
            partb[step & 1][lane] = 0.f;
        }
        buf = nbuf;
    }
}

// ---------------- combine fc2 partials + tanh ----------------
__global__ __launch_bounds__(256) void k_fc2(const float* __restrict__ part,
                                             const float* __restrict__ fc2b,
                                             float* __restrict__ out) {
    int u = blockIdx.x * 256 + threadIdx.x;
    if (u >= BATCH * T2) return;
    int b = u / T2, t = u - b * T2;
    float p = part[(size_t)t * BATCH + b] + part[((size_t)T2 + t) * BATCH + b] + fc2b[0];
    out[u] = tanh_(p);
}

extern "C" void kernel_launch(void* const* d_in, const int* in_sizes, int n_in,
                              void* d_out, int out_size, void* d_ws, size_t ws_size,
                              hipStream_t stream) {
    const float* x      = (const float*)d_in[0];
    const float* fc1w   = (const float*)d_in[1];
    const float* fc1b   = (const float*)d_in[2];
    const float* r1wihf = (const float*)d_in[3];
    const float* r1whhf = (const float*)d_in[4];
    const float* r1bf   = (const float*)d_in[5];
    const float* r1wihb = (const float*)d_in[6];
    const float* r1whhb = (const float*)d_in[7];
    const float* r1bb   = (const float*)d_in[8];
    const float* r2wihf = (const float*)d_in[9];
    const float* r2whhf = (const float*)d_in[10];
    const float* r2bf   = (const float*)d_in[11];
    const float* r2wihb = (const float*)d_in[12];
    const float* r2whhb = (const float*)d_in[13];
    const float* r2bb   = (const float*)d_in[14];
    const float* fc2w   = (const float*)d_in[15];
    const float* fc2b   = (const float*)d_in[16];
    char* ws   = (char*)d_ws;
    float* out = (float*)d_out;

    float*          fc1T  = (float*)(ws + OFF_FC1T);
    unsigned short* XF    = (unsigned short*)(ws + OFF_XF);
    unsigned short* WA1   = (unsigned short*)(ws + OFF_WA1);
    unsigned short* WA2HH = (unsigned short*)(ws + OFF_WA2HH);
    unsigned short* WA2IH = (unsigned short*)(ws + OFF_WA2IH);
    float*          partp = (float*)(ws + OFF_PART);

    k_prep<<<64, 256, 0, stream>>>(r1whhf, r1whhb, r2whhf, r2whhb, r2wihf, r2wihb,
                                   WA1, WA2HH, WA2IH);
    k_fc1<<<BATCH / 256, 256, 0, stream>>>(x, fc1w, fc1b, fc1T);
    dim3 g1(NBLK, 2);
    k_lstm1<<<g1, 512, 0, stream>>>(r1wihf, r1bf, r1wihb, r1bb, WA1, fc1T, XF);
    k_lstm2<<<g1, 512, 0, stream>>>(r2bf, r2bb, fc2w, WA2HH, WA2IH, XF, partp);
    k_fc2<<<(BATCH * T2 + 255) / 256, 256, 0, stream>>>(partp, fc2b, out);
}

// Round 3
// 388.966 us; speedup vs baseline: 6.0322x; 1.4864x over previous
//
#include <hip/hip_runtime.h>
#include <cmath>

#define H1    64
#define T1    50
#define T2    100
#define BATCH 8192
#define NB2   256        // sample-blocks of 32
#define NTILE 512        // global 16-sample tiles

typedef __attribute__((ext_vector_type(8))) short s16x8;
typedef __attribute__((ext_vector_type(4))) float f32x4;

#define MFMA16(a,b,c) __builtin_amdgcn_mfma_f32_16x16x32_bf16(a,b,c,0,0,0)

#define S_SIG  (-1.4426950408889634f)   // -1/ln2 : sigmoid gates (i,f,o)
#define S_TANH ( 2.8853900817779268f)   // +2/ln2 : tanh gate (g)

// ---- workspace byte offsets ----
#define OFF_FC1T  ((size_t)0)                                   // fp32 T1*BATCH
#define OFF_XF    ((size_t)1638400)                             // ushort T1*4*NTILE*64*8
#define OFF_WA1   ((size_t)(1638400 + 104857600))               // ushort 32768
#define OFF_WA2HH (OFF_WA1 + 65536)                             // ushort 32768
#define OFF_WA2IH (OFF_WA2HH + 65536)                           // ushort 65536
#define OFF_PART  (OFF_WA2IH + 131072)                          // fp32 2*T2*BATCH

__device__ __forceinline__ float rcp_(float x) { return __builtin_amdgcn_rcpf(x); }
__device__ __forceinline__ float exp2_(float x) {
#if __has_builtin(__builtin_amdgcn_exp2f)
    return __builtin_amdgcn_exp2f(x);
#else
    return exp2f(x);
#endif
}
// inputs pre-scaled: e = S_SIG*x for sigp_, e = S_TANH*x for tanhp_
__device__ __forceinline__ float sigp_(float e)  { return rcp_(1.f + exp2_(e)); }
__device__ __forceinline__ float tanhp_(float e) { return 1.f - 2.f * rcp_(1.f + exp2_(e)); }
__device__ __forceinline__ float tanhc_(float c) { return tanhp_(S_TANH * c); }
__device__ __forceinline__ float tanh_(float x)  { return tanhc_(x); }

__device__ __forceinline__ unsigned short bf16_rne(float x) {
    unsigned int u = __float_as_uint(x);
    u += 0x7fffu + ((u >> 16) & 1u);
    return (unsigned short)(u >> 16);
}
__device__ __forceinline__ float bf16f(unsigned short h) {
    return __uint_as_float(((unsigned int)h) << 16);
}

// ---------------- prep: weights -> bf16 A-fragment layout, PRE-SCALED per gate ----------------
// A-frag (16x16x32): lane l holds A[m = l&15][k = (l>>4)*8 + j], j=0..7
// WA1 / WA2HH: [dir][mt(16)][kk(2)][l(64)][j(8)];  WA2IH: [dir][mt(16)][kk(4)][l(64)][j(8)]
__global__ __launch_bounds__(256) void k_prep(
    const float* __restrict__ whh1f, const float* __restrict__ whh1b,
    const float* __restrict__ whh2f, const float* __restrict__ whh2b,
    const float* __restrict__ wih2f, const float* __restrict__ wih2b,
    unsigned short* __restrict__ WA1, unsigned short* __restrict__ WA2HH,
    unsigned short* __restrict__ WA2IH)
{
    int i = blockIdx.x * 256 + threadIdx.x;     // 16384 slots
    if (i < 8192) {
        int a   = i >> 12;                      // 0: layer1 whh, 1: layer2 whh
        int r   = i & 4095;
        int dir = r >> 11, rem = r & 2047;
        int mt  = rem >> 7, rem2 = rem & 127;
        int kk  = rem2 >> 6, l = rem2 & 63;
        const float* s_ = a ? (dir ? whh2b : whh2f) : (dir ? whh1b : whh1f);
        unsigned short* d_ = a ? WA2HH : WA1;
        int gate = mt * 16 + (l & 15);
        float sc = ((gate >> 6) == 2) ? S_TANH : S_SIG;
        int k0   = kk * 32 + (l >> 4) * 8;
        const float* p = s_ + gate * 64 + k0;
        unsigned short* q = d_ + (size_t)r * 8;
#pragma unroll
        for (int j = 0; j < 8; ++j) q[j] = bf16_rne(p[j] * sc);
    } else {
        int r   = i - 8192;                     // layer2 wih, 8192 slots
        int dir = r >> 12, rem = r & 4095;
        int mt  = rem >> 8, rem2 = rem & 255;
        int kk  = rem2 >> 6, l = rem2 & 63;
        const float* s_ = dir ? wih2b : wih2f;
        int gate = mt * 16 + (l & 15);
        float sc = ((gate >> 6) == 2) ? S_TANH : S_SIG;
        int k0   = kk * 32 + (l >> 4) * 8;
        const float* p = s_ + gate * 128 + k0;
        unsigned short* q = WA2IH + (size_t)r * 8;
#pragma unroll
        for (int j = 0; j < 8; ++j) q[j] = bf16_rne(p[j] * sc);
    }
}

// ---------------- fc1 ----------------
__global__ __launch_bounds__(256) void k_fc1(const float* __restrict__ x,
                                             const float* __restrict__ w,
                                             const float* __restrict__ b,
                                             float* __restrict__ fc1T) {
    __shared__ float wls[1000];
    __shared__ float bls[50];
    int tid = threadIdx.x;
    for (int i = tid; i < 1000; i += 256) wls[i] = w[i];
    if (tid < 50) bls[tid] = b[tid];
    __syncthreads();
    int bidx = blockIdx.x * 256 + tid;
    float xv[20];
#pragma unroll
    for (int i = 0; i < 20; ++i) xv[i] = x[bidx * 20 + i];
    for (int t = 0; t < T1; ++t) {
        float s = bls[t];
#pragma unroll
        for (int i = 0; i < 20; ++i) s += xv[i] * wls[t * 20 + i];
        fc1T[t * BATCH + bidx] = s;
    }
}

// ---------------- layer-1 BiLSTM ----------------
// block (bblk<256, dir); 32 samples/block; 8 waves = wh(4 hidden-groups) x wsh(2 sample-tiles)
__global__ __launch_bounds__(512, 4) void k_lstm1(
    const float* __restrict__ wih1f, const float* __restrict__ b1f,
    const float* __restrict__ wih1b, const float* __restrict__ b1b,
    const unsigned short* __restrict__ WA1,
    const float* __restrict__ fc1T,
    unsigned short* __restrict__ XF)
{
    __shared__ float x1s[T1][32];
    __shared__ unsigned short Htf[2][2][2][2][64][8];   // [buf][half][kk][wsh][l][j] 16KB
    int tid  = threadIdx.x;
    int lane = tid & 63;
    int w    = __builtin_amdgcn_readfirstlane(tid >> 6);
    int wh   = w & 3, wsh = w >> 2;
    int quad = lane >> 4, col = lane & 15;
    int dir  = blockIdx.y, bblk = blockIdx.x;

    for (int i = tid; i < T1 * 32; i += 512) {
        int t = i >> 5, s = i & 31;
        x1s[t][s] = fc1T[t * BATCH + bblk * 32 + s];
    }
    const float* wih = dir ? wih1b : wih1f;
    const float* bia = dir ? b1b : b1f;
    f32x4 wvv[4], bvv[4];
#pragma unroll
    for (int g = 0; g < 4; ++g) {
        float sc = (g == 2) ? S_TANH : S_SIG;
#pragma unroll
        for (int r = 0; r < 4; ++r) {
            int gate = g * 64 + wh * 16 + quad * 4 + r;
            wvv[g][r] = wih[gate] * sc;
            bvv[g][r] = bia[gate] * sc;
        }
    }
    s16x8 whhA[4][2];
#pragma unroll
    for (int g = 0; g < 4; ++g)
#pragma unroll
        for (int kk = 0; kk < 2; ++kk)
            whhA[g][kk] = *(const s16x8*)(WA1 +
                ((size_t)((dir * 16 + (g * 4 + wh)) * 2 + kk) * 64 + lane) * 8);

    float c[4];
#pragma unroll
    for (int r = 0; r < 4; ++r) c[r] = 0.f;

    int lq  = 2 * (wh & 1) + (quad >> 1);
    int lp  = lq * 16 + col;
    int jo  = (quad & 1) * 4;
    int kkw = wh >> 1;
    int kk1 = dir * 2 + (wh >> 1);
    int gtile = bblk * 2 + wsh;
    __syncthreads();
    int buf = 0;
    for (int step = 0; step < T1; ++step) {
        int t = dir ? (T1 - 1 - step) : step;
        float xt = x1s[t][wsh * 16 + col];
        f32x4 acc[4];
#pragma unroll
        for (int g = 0; g < 4; ++g)
#pragma unroll
            for (int r = 0; r < 4; ++r)
                acc[g][r] = bvv[g][r] + wvv[g][r] * xt;
        if (step) {
#pragma unroll
            for (int hf = 0; hf < 2; ++hf) {
                s16x8 hb0 = *(const s16x8*)&Htf[buf][hf][0][wsh][lane][0];
                s16x8 hb1 = *(const s16x8*)&Htf[buf][hf][1][wsh][lane][0];
#pragma unroll
                for (int g = 0; g < 4; ++g) {
                    acc[g] = MFMA16(whhA[g][0], hb0, acc[g]);
                    acc[g] = MFMA16(whhA[g][1], hb1, acc[g]);
                }
            }
        }
        int nbuf = buf ^ 1;
        unsigned short hh[4], hl[4];
#pragma unroll
        for (int r = 0; r < 4; ++r) {
            float cc = sigp_(acc[1][r]) * c[r] + sigp_(acc[0][r]) * tanhp_(acc[2][r]);
            c[r] = cc;
            float h = sigp_(acc[3][r]) * tanhc_(cc);
            hh[r] = bf16_rne(h);
            hl[r] = bf16_rne(h - bf16f(hh[r]));
        }
        uint2 vhi, vlo;
        vhi.x = (unsigned)hh[0] | ((unsigned)hh[1] << 16);
        vhi.y = (unsigned)hh[2] | ((unsigned)hh[3] << 16);
        vlo.x = (unsigned)hl[0] | ((unsigned)hl[1] << 16);
        vlo.y = (unsigned)hl[2] | ((unsigned)hl[3] << 16);
        *(uint2*)&Htf[nbuf][0][kkw][wsh][lp][jo] = vhi;
        *(uint2*)&Htf[nbuf][1][kkw][wsh][lp][jo] = vlo;
        *(uint2*)(XF + ((((size_t)t * 4 + kk1) * NTILE + gtile) * 64 + lp) * 8 + jo) = vhi;
        __syncthreads();
        buf = nbuf;
    }
}

// ---------------- layer-2 BiLSTM + fused fc2 partial ----------------
__global__ __launch_bounds__(512, 4) void k_lstm2(
    const float* __restrict__ b2f, const float* __restrict__ b2b,
    const float* __restrict__ fc2w,
    const unsigned short* __restrict__ WA2HH,
    const unsigned short* __restrict__ WA2IH,
    const unsigned short* __restrict__ XF,
    float* __restrict__ part)
{
    __shared__ unsigned short wAl[16][4][64][8];        // 64KB: dir slice of WA2IH
    __shared__ unsigned short Htf[2][2][2][64][8];      // [half][kk][wsh][l][j] 8KB, single copy
    __shared__ f32x4 biasl[16][4];                      // [mt][quad] prescaled bias
    __shared__ float partb[2][4][16];                   // [wsh][wh][col]
    int tid  = threadIdx.x;
    int lane = tid & 63;
    int w    = __builtin_amdgcn_readfirstlane(tid >> 6);
    int wh   = w & 3, wsh = w >> 2;
    int quad = lane >> 4, col = lane & 15;
    int dir  = blockIdx.y, bblk = blockIdx.x;
    int gtile = bblk * 2 + wsh;

    {   // stage Wih A-fragments (our dir) into LDS
        const uint4* src = (const uint4*)(WA2IH + (size_t)dir * 32768);
        uint4* dst = (uint4*)&wAl[0][0][0][0];
        for (int i = tid; i < 4096; i += 512) dst[i] = src[i];
    }
    const float* bia = dir ? b2b : b2f;
    if (tid < 64) {
        int mt = tid >> 2, q = tid & 3;
        float sc = ((mt >> 2) == 2) ? S_TANH : S_SIG;
        f32x4 v;
#pragma unroll
        for (int r = 0; r < 4; ++r) v[r] = bia[mt * 16 + q * 4 + r] * sc;
        biasl[mt][q] = v;
    }
    float f2v[4];
#pragma unroll
    for (int r = 0; r < 4; ++r)
        f2v[r] = fc2w[dir * 64 + wh * 16 + quad * 4 + r];

    s16x8 whhA[4][2];
#pragma unroll
    for (int g = 0; g < 4; ++g)
#pragma unroll
        for (int kk = 0; kk < 2; ++kk)
            whhA[g][kk] = *(const s16x8*)(WA2HH +
                ((size_t)((dir * 16 + (g * 4 + wh)) * 2 + kk) * 64 + lane) * 8);

    float c[4];
#pragma unroll
    for (int r = 0; r < 4; ++r) c[r] = 0.f;

    int lq  = 2 * (wh & 1) + (quad >> 1);
    int lp  = lq * 16 + col;
    int jo  = (quad & 1) * 4;
    int kkw = wh >> 1;
    f32x4 xacc[4];
    __syncthreads();

    for (int step = 0; step < T2; ++step) {
        int t2 = dir ? (T2 - 1 - step) : step;
        if ((step & 1) == 0) {              // new time-pair: input projection via MFMA
            int tp = t2 >> 1;
#pragma unroll
            for (int g = 0; g < 4; ++g) xacc[g] = biasl[g * 4 + wh][quad];
#pragma unroll
            for (int kk = 0; kk < 4; ++kk) {
                s16x8 xbk = *(const s16x8*)(XF +
                    (((size_t)(tp * 4 + kk) * NTILE + gtile) * 64 + lane) * 8);
#pragma unroll
                for (int g = 0; g < 4; ++g) {
                    s16x8 wa = *(const s16x8*)&wAl[g * 4 + wh][kk][lane][0];
                    xacc[g] = MFMA16(wa, xbk, xacc[g]);
                }
            }
        }
        f32x4 acc[4];
#pragma unroll
        for (int g = 0; g < 4; ++g) acc[g] = xacc[g];
        if (step) {
#pragma unroll
            for (int hf = 0; hf < 2; ++hf) {
                s16x8 hb0 = *(const s16x8*)&Htf[hf][0][wsh][lane][0];
                s16x8 hb1 = *(const s16x8*)&Htf[hf][1][wsh][lane][0];
#pragma unroll
                for (int g = 0; g < 4; ++g) {
                    acc[g] = MFMA16(whhA[g][0], hb0, acc[g]);
                    acc[g] = MFMA16(whhA[g][1], hb1, acc[g]);
                }
            }
        }
        unsigned short hh[4], hl[4];
        float pacc = 0.f;
#pragma unroll
        for (int r = 0; r < 4; ++r) {
            float cc = sigp_(acc[1][r]) * c[r] + sigp_(acc[0][r]) * tanhp_(acc[2][r]);
            c[r] = cc;
            float h = sigp_(acc[3][r]) * tanhc_(cc);
            pacc += f2v[r] * h;
            hh[r] = bf16_rne(h);
            hl[r] = bf16_rne(h - bf16f(hh[r]));
        }
        pacc += __shfl_xor(pacc, 16);
        pacc += __shfl_xor(pacc, 32);
        uint2 vhi, vlo;
        vhi.x = (unsigned)hh[0] | ((unsigned)hh[1] << 16);
        vhi.y = (unsigned)hh[2] | ((unsigned)hh[3] << 16);
        vlo.x = (unsigned)hl[0] | ((unsigned)hl[1] << 16);
        vlo.y = (unsigned)hl[2] | ((unsigned)hl[3] << 16);
        __syncthreads();                    // A: all Htf reads of prev state done
        *(uint2*)&Htf[0][kkw][wsh][lp][jo] = vhi;
        *(uint2*)&Htf[1][kkw][wsh][lp][jo] = vlo;
        if (lane < 16) partb[wsh][wh][lane] = pacc;
        __syncthreads();                    // B: writes visible
        if (tid < 32) {                     // fc2 partial for this dir, 32 samples
            int sw = tid >> 4, sc_ = tid & 15;
            float p = partb[sw][0][sc_] + partb[sw][1][sc_] +
                      partb[sw][2][sc_] + partb[sw][3][sc_];
            part[((size_t)(dir * T2 + t2)) * BATCH + bblk * 32 + tid] = p;
        }
    }
}

// ---------------- combine fc2 partials + tanh ----------------
__global__ __launch_bounds__(256) void k_fc2(const float* __restrict__ part,
                                             const float* __restrict__ fc2b,
                                             float* __restrict__ out) {
    int u = blockIdx.x * 256 + threadIdx.x;
    if (u >= BATCH * T2) return;
    int b = u / T2, t = u - b * T2;
    float p = part[(size_t)t * BATCH + b] + part[((size_t)T2 + t) * BATCH + b] + fc2b[0];
    out[u] = tanh_(p);
}

extern "C" void kernel_launch(void* const* d_in, const int* in_sizes, int n_in,
                              void* d_out, int out_size, void* d_ws, size_t ws_size,
                              hipStream_t stream) {
    const float* x      = (const float*)d_in[0];
    const float* fc1w   = (const float*)d_in[1];
    const float* fc1b   = (const float*)d_in[2];
    const float* r1wihf = (const float*)d_in[3];
    const float* r1whhf = (const float*)d_in[4];
    const float* r1bf   = (const float*)d_in[5];
    const float* r1wihb = (const float*)d_in[6];
    const float* r1whhb = (const float*)d_in[7];
    const float* r1bb   = (const float*)d_in[8];
    const float* r2wihf = (const float*)d_in[9];
    const float* r2whhf = (const float*)d_in[10];
    const float* r2bf   = (const float*)d_in[11];
    const float* r2wihb = (const float*)d_in[12];
    const float* r2whhb = (const float*)d_in[13];
    const float* r2bb   = (const float*)d_in[14];
    const float* fc2w   = (const float*)d_in[15];
    const float* fc2b   = (const float*)d_in[16];
    char* ws   = (char*)d_ws;
    float* out = (float*)d_out;

    float*          fc1T  = (float*)(ws + OFF_FC1T);
    unsigned short* XF    = (unsigned short*)(ws + OFF_XF);
    unsigned short* WA1   = (unsigned short*)(ws + OFF_WA1);
    unsigned short* WA2HH = (unsigned short*)(ws + OFF_WA2HH);
    unsigned short* WA2IH = (unsigned short*)(ws + OFF_WA2IH);
    float*          partp = (float*)(ws + OFF_PART);

    k_prep<<<64, 256, 0, stream>>>(r1whhf, r1whhb, r2whhf, r2whhb, r2wihf, r2wihb,
                                   WA1, WA2HH, WA2IH);
    k_fc1<<<BATCH / 256, 256, 0, stream>>>(x, fc1w, fc1b, fc1T);
    dim3 g1(NB2, 2);
    k_lstm1<<<g1, 512, 0, stream>>>(r1wihf, r1bf, r1wihb, r1bb, WA1, fc1T, XF);
    k_lstm2<<<g1, 512, 0, stream>>>(r2bf, r2bb, fc2w, WA2HH, WA2IH, XF, partp);
    k_fc2<<<(BATCH * T2 + 255) / 256, 256, 0, stream>>>(partp, fc2b, out);
}

// Round 4
// 383.197 us; speedup vs baseline: 6.1230x; 1.0151x over previous
//
#include <hip/hip_runtime.h>
#include <cmath>

#define H1    64
#define T1    50
#define T2    100
#define BATCH 8192
#define NB2   256        // sample-blocks of 32
#define NTILE 512        // global 16-sample tiles

typedef __attribute__((ext_vector_type(8))) short s16x8;
typedef __attribute__((ext_vector_type(4))) float f32x4;

#define MFMA16(a,b,c) __builtin_amdgcn_mfma_f32_16x16x32_bf16(a,b,c,0,0,0)

#define S_SIG  (-1.4426950408889634f)   // -1/ln2 : sigmoid gates (i,f,o)
#define S_TANH ( 2.8853900817779268f)   // +2/ln2 : tanh gate (g)

// ---- workspace byte offsets ----
#define OFF_FC1T  ((size_t)0)                                   // fp32 T1*BATCH
#define OFF_XF    ((size_t)1638400)                             // ushort T1*4*NTILE*64*8
#define OFF_WA1   ((size_t)(1638400 + 104857600))               // ushort 32768
#define OFF_WA2HH (OFF_WA1 + 65536)                             // ushort 32768
#define OFF_WA2IH (OFF_WA2HH + 65536)                           // ushort 65536
#define OFF_PART  (OFF_WA2IH + 131072)                          // fp32 2*T2*BATCH
#define OFF_BS    (OFF_PART + 6553600)                          // fp32 2*256 prescaled bias

__device__ __forceinline__ float rcp_(float x) { return __builtin_amdgcn_rcpf(x); }
__device__ __forceinline__ float exp2_(float x) {
#if __has_builtin(__builtin_amdgcn_exp2f)
    return __builtin_amdgcn_exp2f(x);
#else
    return exp2f(x);
#endif
}
__device__ __forceinline__ float sigp_(float e)  { return rcp_(1.f + exp2_(e)); }
__device__ __forceinline__ float tanhp_(float e) { return 1.f - 2.f * rcp_(1.f + exp2_(e)); }
__device__ __forceinline__ float tanhc_(float c) { return tanhp_(S_TANH * c); }
__device__ __forceinline__ float tanh_(float x)  { return tanhc_(x); }

__device__ __forceinline__ unsigned short bf16_rne(float x) {
    unsigned int u = __float_as_uint(x);
    u += 0x7fffu + ((u >> 16) & 1u);
    return (unsigned short)(u >> 16);
}
__device__ __forceinline__ float bf16f(unsigned short h) {
    return __uint_as_float(((unsigned int)h) << 16);
}

// ---------------- k_pre: weight frags (prescaled) + prescaled bias + fc1 + zero(part) ----------------
// blocks 0..63: weight-frag slots; block 64..95: fc1; blocks 96..351: zero part; block 352: bias table
__global__ __launch_bounds__(256) void k_pre(
    const float* __restrict__ whh1f, const float* __restrict__ whh1b,
    const float* __restrict__ whh2f, const float* __restrict__ whh2b,
    const float* __restrict__ wih2f, const float* __restrict__ wih2b,
    const float* __restrict__ b2f,   const float* __restrict__ b2b,
    const float* __restrict__ x, const float* __restrict__ fc1w,
    const float* __restrict__ fc1b,
    unsigned short* __restrict__ WA1, unsigned short* __restrict__ WA2HH,
    unsigned short* __restrict__ WA2IH, float* __restrict__ fc1T,
    float* __restrict__ part, float* __restrict__ BS)
{
    __shared__ float wls[1000];
    __shared__ float bls[50];
    int tid = threadIdx.x;
    int blk = blockIdx.x;
    if (blk < 64) {
        int i = blk * 256 + tid;                    // 16384 slots
        if (i < 8192) {
            int a   = i >> 12;                      // 0: layer1 whh, 1: layer2 whh
            int r   = i & 4095;
            int dir = r >> 11, rem = r & 2047;
            int mt  = rem >> 7, rem2 = rem & 127;
            int kk  = rem2 >> 6, l = rem2 & 63;
            const float* s_ = a ? (dir ? whh2b : whh2f) : (dir ? whh1b : whh1f);
            unsigned short* d_ = a ? WA2HH : WA1;
            int gate = mt * 16 + (l & 15);
            float sc = ((gate >> 6) == 2) ? S_TANH : S_SIG;
            int k0   = kk * 32 + (l >> 4) * 8;
            const float* p = s_ + gate * 64 + k0;
            unsigned short* q = d_ + (size_t)r * 8;
#pragma unroll
            for (int j = 0; j < 8; ++j) q[j] = bf16_rne(p[j] * sc);
        } else {
            int r   = i - 8192;                     // layer2 wih, 8192 slots
            int dir = r >> 12, rem = r & 4095;
            int mt  = rem >> 8, rem2 = rem & 255;
            int kk  = rem2 >> 6, l = rem2 & 63;
            const float* s_ = dir ? wih2b : wih2f;
            int gate = mt * 16 + (l & 15);
            float sc = ((gate >> 6) == 2) ? S_TANH : S_SIG;
            int k0   = kk * 32 + (l >> 4) * 8;
            const float* p = s_ + gate * 128 + k0;
            unsigned short* q = WA2IH + (size_t)r * 8;
#pragma unroll
            for (int j = 0; j < 8; ++j) q[j] = bf16_rne(p[j] * sc);
        }
    } else if (blk < 96) {
        // fc1
        for (int i = tid; i < 1000; i += 256) wls[i] = fc1w[i];
        if (tid < 50) bls[tid] = fc1b[tid];
        __syncthreads();
        int bidx = (blk - 64) * 256 + tid;
        float xv[20];
#pragma unroll
        for (int i = 0; i < 20; ++i) xv[i] = x[bidx * 20 + i];
        for (int t = 0; t < T1; ++t) {
            float s = bls[t];
#pragma unroll
            for (int i = 0; i < 20; ++i) s += xv[i] * wls[t * 20 + i];
            fc1T[t * BATCH + bidx] = s;
        }
    } else if (blk < 352) {
        // zero the fc2 partial accumulator (atomicAdd target)
        const int n = 2 * T2 * BATCH;
        for (int i = (blk - 96) * 256 + tid; i < n; i += 256 * 256) part[i] = 0.f;
    } else {
        // prescaled layer-2 bias table: BS[dir*256 + m] = bias[m] * sc(m>>6)
        for (int i = tid; i < 512; i += 256) {
            int d = i >> 8, m = i & 255;
            const float* bb = d ? b2b : b2f;
            float sc = ((m >> 6) == 2) ? S_TANH : S_SIG;
            BS[i] = bb[m] * sc;
        }
    }
}

// ---------------- layer-1 BiLSTM (unchanged from R3) ----------------
__global__ __launch_bounds__(512, 4) void k_lstm1(
    const float* __restrict__ wih1f, const float* __restrict__ b1f,
    const float* __restrict__ wih1b, const float* __restrict__ b1b,
    const unsigned short* __restrict__ WA1,
    const float* __restrict__ fc1T,
    unsigned short* __restrict__ XF)
{
    __shared__ float x1s[T1][32];
    __shared__ unsigned short Htf[2][2][2][2][64][8];   // [buf][half][kk][wsh][l][j]
    int tid  = threadIdx.x;
    int lane = tid & 63;
    int w    = __builtin_amdgcn_readfirstlane(tid >> 6);
    int wh   = w & 3, wsh = w >> 2;
    int quad = lane >> 4, col = lane & 15;
    int dir  = blockIdx.y, bblk = blockIdx.x;

    for (int i = tid; i < T1 * 32; i += 512) {
        int t = i >> 5, s = i & 31;
        x1s[t][s] = fc1T[t * BATCH + bblk * 32 + s];
    }
    const float* wih = dir ? wih1b : wih1f;
    const float* bia = dir ? b1b : b1f;
    f32x4 wvv[4], bvv[4];
#pragma unroll
    for (int g = 0; g < 4; ++g) {
        float sc = (g == 2) ? S_TANH : S_SIG;
#pragma unroll
        for (int r = 0; r < 4; ++r) {
            int gate = g * 64 + wh * 16 + quad * 4 + r;
            wvv[g][r] = wih[gate] * sc;
            bvv[g][r] = bia[gate] * sc;
        }
    }
    s16x8 whhA[4][2];
#pragma unroll
    for (int g = 0; g < 4; ++g)
#pragma unroll
        for (int kk = 0; kk < 2; ++kk)
            whhA[g][kk] = *(const s16x8*)(WA1 +
                ((size_t)((dir * 16 + (g * 4 + wh)) * 2 + kk) * 64 + lane) * 8);

    float c[4];
#pragma unroll
    for (int r = 0; r < 4; ++r) c[r] = 0.f;

    int lq  = 2 * (wh & 1) + (quad >> 1);
    int lp  = lq * 16 + col;
    int jo  = (quad & 1) * 4;
    int kkw = wh >> 1;
    int kk1 = dir * 2 + (wh >> 1);
    int gtile = bblk * 2 + wsh;
    __syncthreads();
    int buf = 0;
    for (int step = 0; step < T1; ++step) {
        int t = dir ? (T1 - 1 - step) : step;
        float xt = x1s[t][wsh * 16 + col];
        f32x4 acc[4];
#pragma unroll
        for (int g = 0; g < 4; ++g)
#pragma unroll
            for (int r = 0; r < 4; ++r)
                acc[g][r] = bvv[g][r] + wvv[g][r] * xt;
        if (step) {
#pragma unroll
            for (int hf = 0; hf < 2; ++hf) {
                s16x8 hb0 = *(const s16x8*)&Htf[buf][hf][0][wsh][lane][0];
                s16x8 hb1 = *(const s16x8*)&Htf[buf][hf][1][wsh][lane][0];
#pragma unroll
                for (int g = 0; g < 4; ++g) {
                    acc[g] = MFMA16(whhA[g][0], hb0, acc[g]);
                    acc[g] = MFMA16(whhA[g][1], hb1, acc[g]);
                }
            }
        }
        int nbuf = buf ^ 1;
        unsigned short hh[4], hl[4];
#pragma unroll
        for (int r = 0; r < 4; ++r) {
            float cc = sigp_(acc[1][r]) * c[r] + sigp_(acc[0][r]) * tanhp_(acc[2][r]);
            c[r] = cc;
            float h = sigp_(acc[3][r]) * tanhc_(cc);
            hh[r] = bf16_rne(h);
            hl[r] = bf16_rne(h - bf16f(hh[r]));
        }
        uint2 vhi, vlo;
        vhi.x = (unsigned)hh[0] | ((unsigned)hh[1] << 16);
        vhi.y = (unsigned)hh[2] | ((unsigned)hh[3] << 16);
        vlo.x = (unsigned)hl[0] | ((unsigned)hl[1] << 16);
        vlo.y = (unsigned)hl[2] | ((unsigned)hl[3] << 16);
        *(uint2*)&Htf[nbuf][0][kkw][wsh][lp][jo] = vhi;
        *(uint2*)&Htf[nbuf][1][kkw][wsh][lp][jo] = vlo;
        *(uint2*)(XF + ((((size_t)t * 4 + kk1) * NTILE + gtile) * 64 + lp) * 8 + jo) = vhi;
        __syncthreads();
        buf = nbuf;
    }
}

// ---------------- layer-2 BiLSTM: 1 barrier/step, dbuf Htf, prefetch, atomic fc2 ----------------
__global__ __launch_bounds__(512, 4) void k_lstm2(
    const float* __restrict__ BS,
    const float* __restrict__ fc2w,
    const unsigned short* __restrict__ WA2HH,
    const unsigned short* __restrict__ WA2IH,
    const unsigned short* __restrict__ XF,
    float* __restrict__ part)
{
    __shared__ unsigned short wAl[16][4][64][8];        // 64 KB: dir slice of WA2IH
    __shared__ unsigned short Htf[2][2][2][2][64][8];   // [buf][half][kk][wsh][l][j] 16 KB
    int tid  = threadIdx.x;
    int lane = tid & 63;
    int w    = __builtin_amdgcn_readfirstlane(tid >> 6);
    int wh   = w & 3, wsh = w >> 2;
    int quad = lane >> 4, col = lane & 15;
    int dir  = blockIdx.y, bblk = blockIdx.x;
    int gtile = bblk * 2 + wsh;

    {   // stage Wih A-fragments (our dir) into LDS
        const uint4* src = (const uint4*)(WA2IH + (size_t)dir * 32768);
        uint4* dst = (uint4*)&wAl[0][0][0][0];
        for (int i = tid; i < 4096; i += 512) dst[i] = src[i];
    }
    float f2v[4];
#pragma unroll
    for (int r = 0; r < 4; ++r)
        f2v[r] = fc2w[dir * 64 + wh * 16 + quad * 4 + r];

    s16x8 whhA[4][2];
#pragma unroll
    for (int g = 0; g < 4; ++g)
#pragma unroll
        for (int kk = 0; kk < 2; ++kk)
            whhA[g][kk] = *(const s16x8*)(WA2HH +
                ((size_t)((dir * 16 + (g * 4 + wh)) * 2 + kk) * 64 + lane) * 8);

    const float4* bsp = (const float4*)(BS + dir * 256 + wh * 16 + quad * 4);

    float c[4];
#pragma unroll
    for (int r = 0; r < 4; ++r) c[r] = 0.f;

    int lq  = 2 * (wh & 1) + (quad >> 1);
    int lp  = lq * 16 + col;
    int jo  = (quad & 1) * 4;
    int kkw = wh >> 1;

    // preload pair 0 X-frags
    s16x8 xbC[4], xbN[4];
    {
        int tp0 = dir ? (T1 - 1) : 0;
#pragma unroll
        for (int kk = 0; kk < 4; ++kk)
            xbC[kk] = *(const s16x8*)(XF +
                (((size_t)(tp0 * 4 + kk) * NTILE + gtile) * 64 + lane) * 8);
    }
    f32x4 xacc[4];
    __syncthreads();
    int buf = 0;

    for (int step = 0; step < T2; ++step) {
        int t2 = dir ? (T2 - 1 - step) : step;
        if ((step & 1) == 0) {
            // input projection from preloaded frags
#pragma unroll
            for (int g = 0; g < 4; ++g) {
                float4 bv4 = bsp[g * 16];           // BS + (g*4+wh)*16 + quad*4, stride 64 floats
                f32x4 a; a[0] = bv4.x; a[1] = bv4.y; a[2] = bv4.z; a[3] = bv4.w;
#pragma unroll
                for (int kk = 0; kk < 4; ++kk) {
                    s16x8 wa = *(const s16x8*)&wAl[g * 4 + wh][kk][lane][0];
                    a = MFMA16(wa, xbC[kk], a);
                }
                xacc[g] = a;
            }
            // prefetch next pair
            int tp  = t2 >> 1;
            int tpn = dir ? (tp > 0 ? tp - 1 : 0) : (tp < T1 - 1 ? tp + 1 : T1 - 1);
#pragma unroll
            for (int kk = 0; kk < 4; ++kk)
                xbN[kk] = *(const s16x8*)(XF +
                    (((size_t)(tpn * 4 + kk) * NTILE + gtile) * 64 + lane) * 8);
        }
        f32x4 acc[4];
        if (step) {
            s16x8 hb00 = *(const s16x8*)&Htf[buf][0][0][wsh][lane][0];
            s16x8 hb01 = *(const s16x8*)&Htf[buf][0][1][wsh][lane][0];
            s16x8 hb10 = *(const s16x8*)&Htf[buf][1][0][wsh][lane][0];
            s16x8 hb11 = *(const s16x8*)&Htf[buf][1][1][wsh][lane][0];
#pragma unroll
            for (int g = 0; g < 4; ++g) {
                f32x4 a = MFMA16(whhA[g][0], hb00, xacc[g]);
                a = MFMA16(whhA[g][1], hb01, a);
                a = MFMA16(whhA[g][0], hb10, a);
                a = MFMA16(whhA[g][1], hb11, a);
                acc[g] = a;
            }
        } else {
#pragma unroll
            for (int g = 0; g < 4; ++g) acc[g] = xacc[g];
        }
        int nbuf = buf ^ 1;
        unsigned int uhi[4];
        unsigned short hl[4];
        float pacc = 0.f;
#pragma unroll
        for (int r = 0; r < 4; ++r) {
            float cc = sigp_(acc[1][r]) * c[r] + sigp_(acc[0][r]) * tanhp_(acc[2][r]);
            c[r] = cc;
            float h = sigp_(acc[3][r]) * tanhc_(cc);
            pacc += f2v[r] * h;
            unsigned int u = __float_as_uint(h);
            uhi[r] = u & 0xFFFF0000u;                       // truncation hi
            hl[r]  = bf16_rne(h - __uint_as_float(uhi[r])); // exact residual, rne
        }
        uint2 vhi, vlo;
        vhi.x = (uhi[0] >> 16) | uhi[1];
        vhi.y = (uhi[2] >> 16) | uhi[3];
        vlo.x = (unsigned)hl[0] | ((unsigned)hl[1] << 16);
        vlo.y = (unsigned)hl[2] | ((unsigned)hl[3] << 16);
        *(uint2*)&Htf[nbuf][0][kkw][wsh][lp][jo] = vhi;
        *(uint2*)&Htf[nbuf][1][kkw][wsh][lp][jo] = vlo;
        pacc += __shfl_xor(pacc, 16);
        pacc += __shfl_xor(pacc, 32);
        if (lane < 16)
            atomicAdd(&part[((size_t)(dir * T2 + t2)) * BATCH + bblk * 32 + wsh * 16 + lane], pacc);
        __syncthreads();
        buf = nbuf;
        if (step & 1) {
#pragma unroll
            for (int kk = 0; kk < 4; ++kk) xbC[kk] = xbN[kk];
        }
    }
}

// ---------------- combine + tanh ----------------
__global__ __launch_bounds__(256) void k_fc2(const float* __restrict__ part,
                                             const float* __restrict__ fc2b,
                                             float* __restrict__ out) {
    int u = blockIdx.x * 256 + threadIdx.x;
    if (u >= BATCH * T2) return;
    int b = u / T2, t = u - b * T2;
    float p = part[(size_t)t * BATCH + b] + part[((size_t)T2 + t) * BATCH + b] + fc2b[0];
    out[u] = tanh_(p);
}

extern "C" void kernel_launch(void* const* d_in, const int* in_sizes, int n_in,
                              void* d_out, int out_size, void* d_ws, size_t ws_size,
                              hipStream_t stream) {
    const float* x      = (const float*)d_in[0];
    const float* fc1w   = (const float*)d_in[1];
    const float* fc1b   = (const float*)d_in[2];
    const float* r1wihf = (const float*)d_in[3];
    const float* r1whhf = (const float*)d_in[4];
    const float* r1bf   = (const float*)d_in[5];
    const float* r1wihb = (const float*)d_in[6];
    const float* r1whhb = (const float*)d_in[7];
    const float* r1bb   = (const float*)d_in[8];
    const float* r2wihf = (const float*)d_in[9];
    const float* r2whhf = (const float*)d_in[10];
    const float* r2bf   = (const float*)d_in[11];
    const float* r2wihb = (const float*)d_in[12];
    const float* r2whhb = (const float*)d_in[13];
    const float* r2bb   = (const float*)d_in[14];
    const float* fc2w   = (const float*)d_in[15];
    const float* fc2b   = (const float*)d_in[16];
    char* ws   = (char*)d_ws;
    float* out = (float*)d_out;

    float*          fc1T  = (float*)(ws + OFF_FC1T);
    unsigned short* XF    = (unsigned short*)(ws + OFF_XF);
    unsigned short* WA1   = (unsigned short*)(ws + OFF_WA1);
    unsigned short* WA2HH = (unsigned short*)(ws + OFF_WA2HH);
    unsigned short* WA2IH = (unsigned short*)(ws + OFF_WA2IH);
    float*          partp = (float*)(ws + OFF_PART);
    float*          BS    = (float*)(ws + OFF_BS);

    k_pre<<<353, 256, 0, stream>>>(r1whhf, r1whhb, r2whhf, r2whhb, r2wihf, r2wihb,
                                   r2bf, r2bb, x, fc1w, fc1b,
                                   WA1, WA2HH, WA2IH, fc1T, partp, BS);
    dim3 g1(NB2, 2);
    k_lstm1<<<g1, 512, 0, stream>>>(r1wihf, r1bf, r1wihb, r1bb, WA1, fc1T, XF);
    k_lstm2<<<g1, 512, 0, stream>>>(BS, fc2w, WA2HH, WA2IH, XF, partp);
    k_fc2<<<(BATCH * T2 + 255) / 256, 256, 0, stream>>>(partp, fc2b, out);
}